// Round 1
// baseline (182.214 us; speedup 1.0000x reference)
//
#include <hip/hip_runtime.h>
#include <stdint.h>

typedef signed char i8;
typedef __attribute__((ext_vector_type(4))) float f32x4;
typedef __attribute__((ext_vector_type(4))) int i32x4;

#define XSCALE 32.0f
#define INV_XSCALE (1.0f / 32.0f)

// ---------------- conversion kernels ----------------

__device__ __forceinline__ int q8(float f) {
  float s = rintf(f * XSCALE);
  s = fminf(fmaxf(s, -127.0f), 127.0f);
  return ((int)s) & 0xff;
}

// x fp32 -> i8 (scale 32), 16 elems/thread
__global__ __launch_bounds__(256) void cvt_x_kernel(const float* __restrict__ x,
                                                    i32x4* __restrict__ o, int n16) {
  int i = blockIdx.x * blockDim.x + threadIdx.x;
  int stride = gridDim.x * blockDim.x;
  for (; i < n16; i += stride) {
    const f32x4* p = (const f32x4*)x + (size_t)i * 4;
    f32x4 v0 = p[0], v1 = p[1], v2 = p[2], v3 = p[3];
    i32x4 r;
    r[0] = q8(v0[0]) | (q8(v0[1]) << 8) | (q8(v0[2]) << 16) | (q8(v0[3]) << 24);
    r[1] = q8(v1[0]) | (q8(v1[1]) << 8) | (q8(v1[2]) << 16) | (q8(v1[3]) << 24);
    r[2] = q8(v2[0]) | (q8(v2[1]) << 8) | (q8(v2[2]) << 16) | (q8(v2[3]) << 24);
    r[3] = q8(v3[0]) | (q8(v3[1]) << 8) | (q8(v3[2]) << 16) | (q8(v3[3]) << 24);
    o[i] = r;
  }
}

__device__ __forceinline__ int sg8(float f) {
  return (f > 0.0f ? 1 : (f < 0.0f ? -1 : 0)) & 0xff;
}

// w fp32 -> sign i8 (+1/-1/0), 16 elems/thread
__global__ __launch_bounds__(256) void cvt_w_kernel(const float* __restrict__ w,
                                                    i32x4* __restrict__ o, int n16) {
  int i = blockIdx.x * blockDim.x + threadIdx.x;
  int stride = gridDim.x * blockDim.x;
  for (; i < n16; i += stride) {
    const f32x4* p = (const f32x4*)w + (size_t)i * 4;
    f32x4 v0 = p[0], v1 = p[1], v2 = p[2], v3 = p[3];
    i32x4 r;
    r[0] = sg8(v0[0]) | (sg8(v0[1]) << 8) | (sg8(v0[2]) << 16) | (sg8(v0[3]) << 24);
    r[1] = sg8(v1[0]) | (sg8(v1[1]) << 8) | (sg8(v1[2]) << 16) | (sg8(v1[3]) << 24);
    r[2] = sg8(v2[0]) | (sg8(v2[1]) << 8) | (sg8(v2[2]) << 16) | (sg8(v2[3]) << 24);
    r[3] = sg8(v3[0]) | (sg8(v3[1]) << 8) | (sg8(v3[2]) << 16) | (sg8(v3[3]) << 24);
    o[i] = r;
  }
}

// ---------------- 256x256 i8 MFMA GEMM, triple-buffer, ONE barrier/K-tile ---
// r14 = r13 with the [H] barrier removed. Rationale: per-tile cost is
// ~3100 cyc vs ~1300 cyc of MFMA; the two per-tile barriers lockstep the
// 2 waves/SIMD so read-wait and MFMA never cross-overlap. Merging the
// write-protection barrier into the visibility barrier is safe because:
//  - staging S(t+2) targets buf((t+2)%3) == buf((t-1)%3), whose last
//    reads (tile t-1's Ahi) retire at each wave's WAITL(8) in tile t-1,
//    strictly before that wave reaches BAR(t); staging is issued AFTER
//    BAR(t), so no wave can still have reads in flight on that buffer.
//  - S(t+1)'s visibility: each wave drains its own loads at VMCNT0
//    before BAR(t); BAR(t) then publishes all waves' staged data before
//    the [E] reads of tile t+1's fragments.
// Prologue stages only t0,t1 (t2 is staged inside tile 0's stage slot),
// so exactly one tile's 4 units are outstanding at every [D] -> VMCNT0
// is a counted wait, not a pipeline drain.

__device__ __forceinline__ void load_lds16(const void* g, void* l) {
  __builtin_amdgcn_global_load_lds(
      (const __attribute__((address_space(1))) void*)g,
      (__attribute__((address_space(3))) void*)l,
      16, 0, 0);
}

// stage one 8KB unit (128 rows x 64 cols i8) of a [256][64] tile.
__device__ __forceinline__ void stage_unit(const i8* __restrict__ Gp, int K, int k0,
                                           i8* __restrict__ Tlds, int u, int wave,
                                           int lane) {
  const int base = u * 8192 + wave * 1024;        // physical byte base (wave-uniform)
  const int PA = base + lane * 16;                // this lane's physical bytes
  const int L = PA ^ (((PA >> 7) & 3) << 4);      // logical bytes (involution)
  const int r = L >> 6;                           // tile row (64 i8 per row)
  const int c = L & 63;                           // tile col (16-aligned)
  load_lds16(Gp + (size_t)r * K + k0 + c, Tlds + base);
}

#define BAR __builtin_amdgcn_s_barrier()
#define SGB __builtin_amdgcn_sched_barrier(0)
#define WAITL(N) asm volatile("s_waitcnt lgkmcnt(" #N ")" ::: "memory")
#define VMCNT4 asm volatile("s_waitcnt vmcnt(4)" ::: "memory")
#define VMCNT0 asm volatile("s_waitcnt vmcnt(0)" ::: "memory")

#define READ_A_SET(PTR, DST, MI0)                                               \
  _Pragma("unroll") for (int mi = 0; mi < 4; ++mi)                              \
    DST[mi] = *(const i32x4*)((PTR) + abase + ((MI0) + mi) * 1024);

#define READ_B_SET(PTR, DST)                                                    \
  _Pragma("unroll") for (int ni = 0; ni < 4; ++ni)                              \
    DST[ni] = *(const i32x4*)((PTR) + bbase + ni * 1024);

#define MFMA16(AS, BS, MB)                                                      \
  __builtin_amdgcn_s_setprio(1);                                                \
  _Pragma("unroll") for (int mi = 0; mi < 4; ++mi)                              \
  _Pragma("unroll") for (int ni = 0; ni < 4; ++ni)                              \
    acc[(MB) + mi][ni] = __builtin_amdgcn_mfma_i32_16x16x64_i8(                 \
        AS[mi], BS[ni], acc[(MB) + mi][ni], 0, 0, 0);                           \
  __builtin_amdgcn_s_setprio(0);

// cur = buf(t%3) (PCA/PCB), next = buf((t+1)%3) (PNA/PNB),
// stage target = buf((t+2)%3) (PSA/PSB).
#define DO_TILE(t, PCA, PCB, PNA, PNB, PSA, PSB, BCUR, BNXT)                    \
  {                                                                             \
    READ_A_SET(PCA, Ahi, 4);                     /* [A] 4 lgkm */               \
    WAITL(4); SGB;                               /* [B] Alo,Bcur ready */       \
    MFMA16(Alo, BCUR, 0);                        /* [C] */                      \
    SGB;                                                                        \
    if ((t) + 1 < NT) { VMCNT0; }                /* [D] own S(t+1) landed */    \
    BAR;                                         /* sole barrier this tile */   \
    if ((t) + 2 < NT) {                          /* stage S(t+2), post-BAR */   \
      stage_unit(GA, K, ((t) + 2) * 64, PSA, 0, wave, lane);                    \
      stage_unit(GA, K, ((t) + 2) * 64, PSA, 1, wave, lane);                    \
      stage_unit(GB, K, ((t) + 2) * 64, PSB, 0, wave, lane);                    \
      stage_unit(GB, K, ((t) + 2) * 64, PSB, 1, wave, lane);                    \
    }                                                                           \
    if ((t) + 1 < NT) {                                                         \
      READ_A_SET(PNA, Alo, 0);                   /* [E] 8 lgkm */               \
      READ_B_SET(PNB, BNXT);                                                    \
      WAITL(8); SGB;                             /* retire Ahi only */          \
    } else { WAITL(0); SGB; }                                                   \
    MFMA16(Ahi, BCUR, 4);                        /* [G] */                      \
    SGB;                                                                        \
  }

__global__ __launch_bounds__(512, 2) void bingemm256_kernel(
    const i8* __restrict__ A,      // [M][K] i8 (x * 32)
    const i8* __restrict__ B,      // [N][K] i8 sign
    const float* __restrict__ alpha,
    const float* __restrict__ bias,
    float* __restrict__ C,         // [M][N] fp32
    int M, int N, int K) {
  __shared__ i8 AsmB[3][256 * 64];   // 3 x 16 KB
  __shared__ i8 BsmB[3][256 * 64];   // 3 x 16 KB  (96 KB total)

  const int tid = threadIdx.x;
  const int lane = tid & 63;
  const int wave = tid >> 6;
  const int wm = wave >> 2;   // 0..1
  const int wn = wave & 3;    // 0..3
  const int l15 = lane & 15;

  // XCD-aware swizzle (grid divisible by 8 -> simple bijection)
  const int nwg = gridDim.x;
  const int wg = blockIdx.x;
  const int wgid = ((nwg & 7) == 0) ? ((wg & 7) * (nwg >> 3) + (wg >> 3)) : wg;

  const int nbn = N / 256;
  const int tm = wgid / nbn;
  const int tn = wgid % nbn;

  const i8* GA = A + (size_t)tm * 256 * K;
  const i8* GB = B + (size_t)tn * 256 * K;

  // swizzled ds_read byte offsets (row stride 64B, granule 16B):
  // phys k-part = (kq ^ ((row>>1)&3))<<4, (row>>1)&3 == (l15>>1)&3
  const int kq = lane >> 4;                 // 0..3
  const int kph = ((kq ^ ((l15 >> 1) & 3)) << 4);
  const int abase = (wm * 128 + l15) * 64 + kph;   // + mi*1024 (16 rows)
  const int bbase = (wn * 64 + l15) * 64 + kph;    // + ni*1024

  i32x4 acc[8][4];
#pragma unroll
  for (int i = 0; i < 8; ++i)
#pragma unroll
    for (int j = 0; j < 4; ++j)
#pragma unroll
      for (int q = 0; q < 4; ++q) acc[i][j][q] = 0;

  const int NT = K / 64;

  i32x4 Alo[4], Ahi[4], Bb0[4], Bb1[4];

  i8* qA0 = &AsmB[0][0]; i8* qA1 = &AsmB[1][0]; i8* qA2 = &AsmB[2][0];
  i8* qB0 = &BsmB[0][0]; i8* qB1 = &BsmB[1][0]; i8* qB2 = &BsmB[2][0];

  // ---- prologue: stage t0->buf0, t1->buf1; retire t0; preload tile0 frags --
  stage_unit(GA, K, 0, qA0, 0, wave, lane);
  stage_unit(GA, K, 0, qA0, 1, wave, lane);
  stage_unit(GB, K, 0, qB0, 0, wave, lane);
  stage_unit(GB, K, 0, qB0, 1, wave, lane);
  stage_unit(GA, K, 64, qA1, 0, wave, lane);
  stage_unit(GA, K, 64, qA1, 1, wave, lane);
  stage_unit(GB, K, 64, qB1, 0, wave, lane);
  stage_unit(GB, K, 64, qB1, 1, wave, lane);
  VMCNT4;   // retires t0's 4 units exactly; keeps t1's 4 in flight
  BAR;
  READ_A_SET(qA0, Alo, 0);   // tile0 A0-3
  READ_B_SET(qB0, Bb0);      // tile0 B0-3  (8 lgkm outstanding)

  for (int t = 0; t < NT; t += 2) {
    DO_TILE(t,     qA0, qB0, qA1, qB1, qA2, qB2, Bb0, Bb1);
    DO_TILE(t + 1, qA1, qB1, qA2, qB2, qA0, qB0, Bb1, Bb0);
    i8* tA = qA2; qA2 = qA1; qA1 = qA0; qA0 = tA;
    i8* tB = qB2; qB2 = qB1; qB1 = qB0; qB0 = tB;
  }

  // ---- epilogue: C = acc * alpha[col]/32 + bias[col] (nontemporal) ----
  const int r0 = tm * 256 + wm * 128 + ((lane >> 4) << 2);
  const int c0 = tn * 256 + wn * 64 + l15;
#pragma unroll
  for (int an = 0; an < 4; ++an) {
    const int col = c0 + an * 16;
    const float al = alpha[col] * INV_XSCALE;
    const float bi = bias[col];
#pragma unroll
    for (int am = 0; am < 8; ++am) {
#pragma unroll
      for (int j = 0; j < 4; ++j) {
        __builtin_nontemporal_store((float)acc[am][an][j] * al + bi,
                                    &C[(size_t)(r0 + am * 16 + j) * N + col]);
      }
    }
  }
}

// ---------------- fallback (insurance: ws too small / bad dims) ----------------

__global__ __launch_bounds__(256) void naive_kernel(
    const float* __restrict__ x, const float* __restrict__ w,
    const float* __restrict__ alpha, const float* __restrict__ bias,
    float* __restrict__ out, int M, int N, int K) {
  long idx = (long)blockIdx.x * blockDim.x + threadIdx.x;
  const long total = (long)M * N;
  const long stride = (long)gridDim.x * blockDim.x;
  for (; idx < total; idx += stride) {
    const int m = (int)(idx / N);
    const int n = (int)(idx % N);
    const float* xr = x + (size_t)m * K;
    const float* wr = w + (size_t)n * K;
    float s = 0.0f;
    for (int k = 0; k < K; ++k) {
      const float wv = wr[k];
      const float sg = (wv > 0.0f) ? 1.0f : ((wv < 0.0f) ? -1.0f : 0.0f);
      s += xr[k] * sg;
    }
    out[idx] = s * alpha[n] + bias[n];
  }
}

// ---------------- launcher ----------------

extern "C" void kernel_launch(void* const* d_in, const int* in_sizes, int n_in,
                              void* d_out, int out_size, void* d_ws, size_t ws_size,
                              hipStream_t stream) {
  const float* x = (const float*)d_in[0];
  const float* w = (const float*)d_in[1];
  const float* alpha = (const float*)d_in[2];
  const float* bias = (const float*)d_in[3];
  float* out = (float*)d_out;

  const int OUT = in_sizes[3];                // bias length
  const int IN = in_sizes[1] / OUT;           // weight is [OUT][IN]
  const int M = in_sizes[0] / IN;             // x is [B][IN]
  const int N = OUT, K = IN;

  const size_t xbytes = (size_t)M * K;        // i8
  const size_t wbytes = (size_t)N * K;        // i8
  const bool ok = (ws_size >= xbytes + wbytes) &&
                  (M % 256 == 0) && (N % 256 == 0) && (K % 128 == 0) &&
                  (K >= 256) && (K % 16 == 0);

  if (!ok) {
    naive_kernel<<<2048, 256, 0, stream>>>(x, w, alpha, bias, out, M, N, K);
    return;
  }

  i8* xb = (i8*)d_ws;
  i8* wb = xb + xbytes;

  cvt_x_kernel<<<2048, 256, 0, stream>>>(x, (i32x4*)xb, (int)((size_t)M * K / 16));
  cvt_w_kernel<<<2048, 256, 0, stream>>>(w, (i32x4*)wb, (int)((size_t)N * K / 16));

  const int grid = (M / 256) * (N / 256);
  bingemm256_kernel<<<grid, 512, 0, stream>>>(xb, wb, alpha, bias, out, M, N, K);
}